// Round 2
// baseline (71.432 us; speedup 1.0000x reference)
//
#include <hip/hip_runtime.h>
#include <hip/hip_bf16.h>

// Problem constants (fixed by setup_inputs)
#define BB 32
#define NN 2000
#define CC 80
#define NC 160000   // N*C
#define PP 360
#define KK 300
#define NBIN 2048

// Output layout (f32 elements), harness concat in return order:
// labels  [B,K]        @ 0
// boxes   [B,K,4]      @ 9600
// coords  [B,K,P,2]    @ 48000
// scores  [B,K]        @ 6960000
#define OFF_BOXES  (BB*KK)
#define OFF_COORDS (BB*KK + BB*KK*4)
#define OFF_SCORES (BB*KK + BB*KK*4 + BB*KK*PP*2)

__device__ __forceinline__ unsigned flipf(float f) {
    unsigned u = __float_as_uint(f);
    return (u & 0x80000000u) ? ~u : (u | 0x80000000u);
}

// ---------------- Kernel A1: per-batch 2048-bin histogram of key>>21 ----------------
extern "C" __global__ __launch_bounds__(256)
void hist1_kernel(const float* __restrict__ logits, unsigned* __restrict__ ghist) {
    const int b = blockIdx.y;
    __shared__ unsigned h[NBIN];
    for (int i = threadIdx.x; i < NBIN; i += 256) h[i] = 0;
    __syncthreads();
    const int chunkF4 = (NC / 4) / 8;  // 5000 float4 per block, 8 blocks per batch
    const float4* src = (const float4*)(logits + (size_t)b * NC) + (size_t)blockIdx.x * chunkF4;
    for (int i = threadIdx.x; i < chunkF4; i += 256) {
        float4 v = src[i];
        atomicAdd(&h[flipf(v.x) >> 21], 1u);
        atomicAdd(&h[flipf(v.y) >> 21], 1u);
        atomicAdd(&h[flipf(v.z) >> 21], 1u);
        atomicAdd(&h[flipf(v.w) >> 21], 1u);
    }
    __syncthreads();
    for (int i = threadIdx.x; i < NBIN; i += 256) {
        unsigned v = h[i];
        if (v) atomicAdd(&ghist[(size_t)b * NBIN + i], v);
    }
}

// ---------------- Kernel A2: per-batch exact top-K select + labels/scores/boxes ----------------
extern "C" __global__ __launch_bounds__(1024)
void select_kernel(const float* __restrict__ logits, const float* __restrict__ boxes,
                   const float* __restrict__ sizes, const unsigned* __restrict__ ghist,
                   float* __restrict__ out, int* __restrict__ qidx_ws) {
    const int b = blockIdx.x;
    const int tid = threadIdx.x;
    __shared__ unsigned suf[NBIN];
    __shared__ unsigned poolKey[4096];
    __shared__ unsigned poolIdx[4096];
    __shared__ unsigned long long cand[512];
    __shared__ unsigned nCand, nPool, sSelBin, sCntAbove, sSelBin2;

    // --- level-1: load hist, inclusive suffix scan (Kogge-Stone, 2 elems/thread) ---
    suf[tid]        = ghist[(size_t)b * NBIN + tid];
    suf[tid + 1024] = ghist[(size_t)b * NBIN + tid + 1024];
    __syncthreads();
    for (unsigned off = 1; off < NBIN; off <<= 1) {
        unsigned t0 = suf[tid]        + ((tid + off < NBIN)        ? suf[tid + off]        : 0);
        unsigned t1 = suf[tid + 1024] + ((tid + 1024 + off < NBIN) ? suf[tid + 1024 + off] : 0);
        __syncthreads();
        suf[tid] = t0; suf[tid + 1024] = t1;
        __syncthreads();
    }
    // selBin = max bin with suffix >= K
    #pragma unroll
    for (int e = 0; e < 2; e++) {
        int bn = tid + e * 1024;
        if (suf[bn] >= KK && (bn == NBIN - 1 || suf[bn + 1] < KK)) {
            sSelBin = (unsigned)bn;
            sCntAbove = (bn == NBIN - 1) ? 0u : suf[bn + 1];
        }
    }
    if (tid == 0) { nCand = 0; nPool = 0; }
    __syncthreads();
    const unsigned selBin = sSelBin;
    const unsigned cntAbove = sCntAbove;   // # elements with bin > selBin (< K)
    // zero hist2 (reuse suf) and cand
    suf[tid] = 0; suf[tid + 1024] = 0;
    if (tid < 512) cand[tid] = 0ull;
    __syncthreads();

    // --- scan 2: definite-top -> cand; boundary bin -> pool + level-2 hist ---
    const float4* src = (const float4*)(logits + (size_t)b * NC);
    for (int i = tid; i < NC / 4; i += 1024) {
        float4 v = src[i];
        #pragma unroll
        for (int j = 0; j < 4; j++) {
            float x = (j == 0) ? v.x : (j == 1) ? v.y : (j == 2) ? v.z : v.w;
            unsigned key = flipf(x);
            unsigned bin = key >> 21;
            if (bin > selBin) {
                unsigned pos = atomicAdd(&nCand, 1u);
                if (pos < 512)
                    cand[pos] = ((unsigned long long)key << 32) | (unsigned)~(unsigned)(i * 4 + j);
            } else if (bin == selBin) {
                unsigned pos = atomicAdd(&nPool, 1u);
                if (pos < 4096) { poolKey[pos] = key; poolIdx[pos] = (unsigned)(i * 4 + j); }
                atomicAdd(&suf[(key >> 10) & 0x7FFu], 1u);
            }
        }
    }
    __syncthreads();

    // --- level-2 suffix scan over hist2 ---
    for (unsigned off = 1; off < NBIN; off <<= 1) {
        unsigned t0 = suf[tid]        + ((tid + off < NBIN)        ? suf[tid + off]        : 0);
        unsigned t1 = suf[tid + 1024] + ((tid + 1024 + off < NBIN) ? suf[tid + 1024 + off] : 0);
        __syncthreads();
        suf[tid] = t0; suf[tid + 1024] = t1;
        __syncthreads();
    }
    const unsigned target = KK - cntAbove;   // >= 1
    #pragma unroll
    for (int e = 0; e < 2; e++) {
        int bn = tid + e * 1024;
        if (suf[bn] >= target && (bn == NBIN - 1 || suf[bn + 1] < target)) sSelBin2 = (unsigned)bn;
    }
    __syncthreads();
    const unsigned selBin2 = sSelBin2;

    // --- filter pool at 22-bit threshold (>= includes boundary; extras sort out) ---
    const unsigned npool = min(nPool, 4096u);
    for (unsigned i = tid; i < npool; i += 1024) {
        unsigned key = poolKey[i];
        if (((key >> 10) & 0x7FFu) >= selBin2) {
            unsigned pos = atomicAdd(&nCand, 1u);
            if (pos < 512)
                cand[pos] = ((unsigned long long)key << 32) | (unsigned)~poolIdx[i];
        }
    }
    __syncthreads();

    // --- bitonic sort 512 u64 descending: (key desc, idx asc via ~idx) ---
    for (unsigned k2 = 2; k2 <= 512; k2 <<= 1) {
        for (unsigned j = k2 >> 1; j > 0; j >>= 1) {
            if (tid < 512) {
                unsigned i = tid, ixj = i ^ j;
                if (ixj > i) {
                    unsigned long long a = cand[i], c = cand[ixj];
                    bool up = (i & k2) == 0;
                    if (up ? (a < c) : (a > c)) { cand[i] = c; cand[ixj] = a; }
                }
            }
            __syncthreads();
        }
    }

    // --- emit labels, scores, boxes, qidx (all f32) ---
    if (tid < KK) {
        unsigned long long cc = cand[tid];
        unsigned idx = ~(unsigned)(cc & 0xFFFFFFFFull);
        float x = logits[(size_t)b * NC + idx];
        float score = 1.0f / (1.0f + expf(-x));
        int label = (int)(idx % CC) + 1;
        int q = (int)(idx / CC);
        int ok = b * KK + tid;
        out[ok] = (float)label;
        out[OFF_SCORES + ok] = score;
        qidx_ws[ok] = q;
        float s0 = sizes[b * 2 + 0], s1 = sizes[b * 2 + 1];
        float4 bx = ((const float4*)boxes)[(size_t)b * NN + q];  // cx,cy,w,h
        float hw = 0.5f * bx.z, hh = 0.5f * bx.w;
        float4 ob;
        ob.x = (bx.x - hw) * s0;
        ob.y = (bx.y - hh) * s1;
        ob.z = (bx.x + hw) * s0;
        ob.w = (bx.y + hh) * s1;
        ((float4*)(out + OFF_BOXES))[ok] = ob;
    }
}

// ---------------- Kernel B: gather + scale coords [B,K,P,2] f32 ----------------
extern "C" __global__ __launch_bounds__(256)
void gather_coords_kernel(const float* __restrict__ coords, const float* __restrict__ sizes,
                          const int* __restrict__ qidx_ws, float* __restrict__ out) {
    const int bk = blockIdx.x;           // 0 .. B*K-1
    const int b = bk / KK;
    const int q = qidx_ws[bk];
    const float s0 = sizes[b * 2 + 0], s1 = sizes[b * 2 + 1];
    // 720 floats per (b,k) = 180 float4; both src and dst 16B-aligned
    const float4* __restrict__ src = (const float4*)(coords + ((size_t)(b * NN + q)) * (PP * 2));
    float4* __restrict__ dst = (float4*)(out + OFF_COORDS + (size_t)bk * (PP * 2));
    for (int i = threadIdx.x; i < PP / 2; i += 256) {
        float4 v = src[i];
        v.x *= s0; v.y *= s1; v.z *= s0; v.w *= s1;
        dst[i] = v;
    }
}

extern "C" void kernel_launch(void* const* d_in, const int* in_sizes, int n_in,
                              void* d_out, int out_size, void* d_ws, size_t ws_size,
                              hipStream_t stream) {
    const float* logits = (const float*)d_in[0];   // [B,N,C] f32
    const float* coords = (const float*)d_in[1];   // [B,N,P,2] f32
    const float* boxes  = (const float*)d_in[2];   // [B,N,4] f32
    const float* osize  = (const float*)d_in[3];   // [B,2] f32 (w,h)
    // d_in[4] = input_sizes: unused by reference path
    float* out = (float*)d_out;

    unsigned* ghist = (unsigned*)d_ws;                              // B*2048 u32
    int* qidx = (int*)((char*)d_ws + (size_t)BB * NBIN * 4);        // B*K i32

    hipMemsetAsync(d_ws, 0, (size_t)BB * NBIN * 4, stream);
    hist1_kernel<<<dim3(8, BB), 256, 0, stream>>>(logits, ghist);
    select_kernel<<<BB, 1024, 0, stream>>>(logits, boxes, osize, ghist, out, qidx);
    gather_coords_kernel<<<BB * KK, 256, 0, stream>>>(coords, osize, qidx, out);
}